// Round 9
// baseline (368.852 us; speedup 1.0000x reference)
//
#include <hip/hip_runtime.h>
#include <hip/hip_bf16.h>
#include <cstdint>
#include <cstddef>

#define N_NODES 50000
#define N_EDGES 640000
#define ROWS    100000   // B * N_NODES
#define HID     128
#define OUTD    16
#define AGG_BLOCKS 2048
#define MID_BLOCKS 32
#define SCAN_BLOCKS 196  // ceil(50000/256)
#define GEMM_BLOCKS 512
#define GEMM_TILES  (ROWS / 16)   // 6250
#define EG_BLOCKS   3500          // fused edge(2500) + gemm1(1000), 5:2 interleave
#define EG_GEMM_WAVES 4000        // 1000 blocks * 4 waves

// ---------- types ----------
typedef __attribute__((ext_vector_type(8))) uint16_t ushort8;
typedef __attribute__((ext_vector_type(8))) __bf16   bf16x8;
typedef __attribute__((ext_vector_type(4))) float    floatx4;

union FragU { ushort8 u; bf16x8 b; };

// ---------- bf16 helpers ----------
__device__ __forceinline__ float bf_lo(uint32_t u){
  union { uint32_t u; float f; } c; c.u = u << 16; return c.f;
}
__device__ __forceinline__ float bf_hi(uint32_t u){
  union { uint32_t u; float f; } c; c.u = u & 0xffff0000u; return c.f;
}
__device__ __forceinline__ uint16_t f2bf(float f){
  union { float f; uint32_t u; } c; c.f = f;
  uint32_t u = c.u;
  uint32_t r = (u + 0x7fffu + ((u >> 16) & 1u)) >> 16;  // RNE
  return (uint16_t)r;
}

// ---------- W pack (paired-column B-frag mapping), shared by initpack/prep2 ----------
// c-tile c, in-tile col m -> actual col (c>>1)*32 + 2m + (c&1)  (adjacent-col acc pairs)
__device__ __forceinline__ void pack_w(int t, const float* __restrict__ W,
                                       const float* sca /*LDS or null*/,
                                       uint16_t* __restrict__ WP){
  int L = t & 63;
  int s = (t >> 6) & 3;
  int c = t >> 8;
  int n = (c >> 1) * 32 + 2 * (L & 15) + (c & 1);
  int k0 = s * 32 + (L >> 4) * 8;
  ushort8 r;
#pragma unroll
  for (int j = 0; j < 8; j++){
    float w = W[(size_t)(k0 + j) * HID + n];
    if (sca) w *= sca[k0 + j];
    r[j] = f2bf(w);
  }
  *((ushort8*)(WP + (size_t)t * 8)) = r;
}

// ---------- launch 1: zero DC + pack W1 ----------
__global__ void k_initpack(unsigned long long* __restrict__ dc,
                           const float* __restrict__ W1, uint16_t* __restrict__ WP1){
  int b = blockIdx.x;
  if (b < SCAN_BLOCKS){
    int i = b * 256 + threadIdx.x;
    if (i < N_NODES) dc[i] = 0ull;
  } else {
    pack_w((b - SCAN_BLOCKS) * 256 + threadIdx.x, W1, nullptr, WP1);
  }
}

// ---------- launch 2: fused edge-degree atomics + GEMM1 (independent, overlap; 5:2) ----------
// DC[i]: bits[63:44] = in-degree count, bits[43:0] = sum(w) in 2^20 fixed point.
__global__ __launch_bounds__(256, 4) void k_edge_gemm1(const int* __restrict__ ei,
                                                       const float* __restrict__ ewp,
                                                       unsigned long long* __restrict__ dc,
                                                       unsigned int* __restrict__ slot,
                                                       const float* __restrict__ X,
                                                       const uint16_t* __restrict__ WP,
                                                       uint16_t* __restrict__ Y){
  const int b = blockIdx.x;
  const int g = b % 7;
  if (g < 5){
    // ---- edge part: block eb handles 256 edges ----
    const int eb = (b / 7) * 5 + g;              // 0..2499
    const int e = eb * 256 + threadIdx.x;        // < 640000 exactly
    float w = expf(ewp[e]);
    int c = ei[N_EDGES + e];
    unsigned long long inc = (1ull << 44) | (unsigned long long)(w * 1048576.0f + 0.5f);
    unsigned long long old = atomicAdd(&dc[c], inc);
    slot[e] = (unsigned int)(old >> 44);
    return;
  }
  // ---- gemm1 part: bf16(x) @ W1' -> XW planar ----
  const int lane = threadIdx.x & 63;
  const int wid  = threadIdx.x >> 6;
  const int gw   = ((b / 7) * 2 + (g - 5)) * 4 + wid;   // 0..3999
  const int m    = lane & 15;
  const int kq   = lane >> 4;

  FragU wf[8][4];
#pragma unroll
  for (int c = 0; c < 8; c++)
#pragma unroll
    for (int s = 0; s < 4; s++)
      wf[c][s].u = *((const ushort8*)(WP + (size_t)(((c * 4 + s) * 64 + lane) * 8)));

  uint32_t* Yu = (uint32_t*)Y;
  for (int t = gw; t < GEMM_TILES; t += EG_GEMM_WAVES){
    const int row0 = t * 16;
    FragU af[4];
#pragma unroll
    for (int s = 0; s < 4; s++){
      const float* p = X + (size_t)(row0 + m) * HID + s * 32 + kq * 8;
      floatx4 f0 = *((const floatx4*)p);
      floatx4 f1 = *((const floatx4*)(p + 4));
      ushort8 r;
#pragma unroll
      for (int j = 0; j < 4; j++){ r[j] = f2bf(f0[j]); r[j + 4] = f2bf(f1[j]); }
      af[s].u = r;
    }
    floatx4 acc[8];
#pragma unroll
    for (int c = 0; c < 8; c++) acc[c] = floatx4{0.f, 0.f, 0.f, 0.f};
#pragma unroll
    for (int s = 0; s < 4; s++)
#pragma unroll
      for (int c = 0; c < 8; c++)
        acc[c] = __builtin_amdgcn_mfma_f32_16x16x32_bf16(af[s].b, wf[c][s].b, acc[c], 0, 0, 0);
#pragma unroll
    for (int t4 = 0; t4 < 4; t4++)
#pragma unroll
      for (int i = 0; i < 4; i++){
        uint32_t pr = (uint32_t)f2bf(acc[2 * t4][i]) | ((uint32_t)f2bf(acc[2 * t4 + 1][i]) << 16);
        Yu[(size_t)(row0 + kq * 4 + i) * 64 + t4 * 16 + m] = pr;
      }
  }
}

// ---------- launch 3: unpack DC -> dinv, block-sum counts ----------
__global__ void k_scan_bsum(const unsigned long long* __restrict__ dc, int* __restrict__ bsum,
                            float* __restrict__ dinv){
  __shared__ int sd[256];
  int tid = threadIdx.x;
  int i = blockIdx.x * 256 + tid;
  int cnt = 0;
  if (i < N_NODES){
    unsigned long long v = dc[i];
    cnt = (int)(v >> 44);
    float deg = 1.0f + (float)((double)(v & ((1ull << 44) - 1)) * (1.0 / 1048576.0));
    dinv[i] = 1.0f / sqrtf(deg);
  }
  sd[tid] = cnt;
  __syncthreads();
  for (int off = 128; off > 0; off >>= 1){
    if (tid < off) sd[tid] += sd[tid + off];
    __syncthreads();
  }
  if (tid == 0) bsum[blockIdx.x] = sd[0];
}

// ---------- launch 4: fused block-offset reduce + intra-block scan -> rp ----------
__global__ void k_scan_write(const unsigned long long* __restrict__ dc, const int* __restrict__ bsum,
                             int* __restrict__ rp){
  __shared__ int sb[256];
  __shared__ int sd[256];
  int tid = threadIdx.x;
  sb[tid] = (tid < SCAN_BLOCKS && tid < blockIdx.x) ? bsum[tid] : 0;
  __syncthreads();
  for (int off = 128; off > 0; off >>= 1){
    if (tid < off) sb[tid] += sb[tid + off];
    __syncthreads();
  }
  const int base = sb[0];

  int i = blockIdx.x * 256 + tid;
  int v = (i < N_NODES) ? (int)(dc[i] >> 44) : 0;
  sd[tid] = v;
  __syncthreads();
  for (int off = 1; off < 256; off <<= 1){
    int t = (tid >= off) ? sd[tid - off] : 0;
    __syncthreads();
    sd[tid] += t;
    __syncthreads();
  }
  if (i < N_NODES) rp[i] = base + sd[tid] - v;
  if (blockIdx.x == 0 && tid == 0) rp[N_NODES] = N_EDGES;
}

// ---------- launch 5: fill CSR with packed record (norm<<32 | src); slot known -> NO atomic ----------
__global__ void k_fill(const int* __restrict__ ei, const float* __restrict__ ewp,
                       const float* __restrict__ dinv, const unsigned int* __restrict__ slot,
                       const int* __restrict__ rp, unsigned long long* __restrict__ edg){
  int e = blockIdx.x * 256 + threadIdx.x;
  if (e < N_EDGES){
    int r = ei[e];
    int c = ei[N_EDGES + e];
    float w = expf(ewp[e]);
    float nrm = dinv[r] * w * dinv[c];
    int p = rp[c] + (int)slot[e];
    edg[p] = ((unsigned long long)__float_as_uint(nrm) << 32) | (unsigned int)r;
  }
}

// ---------- standalone GEMM2: bf16 H @ W2' -> XW planar ----------
__global__ __launch_bounds__(256, 2) void k_gemm2(const uint16_t* __restrict__ X,
                                                  const uint16_t* __restrict__ WP,
                                                  uint16_t* __restrict__ Y){
  const int lane = threadIdx.x & 63;
  const int wid  = threadIdx.x >> 6;
  const int gw   = blockIdx.x * 4 + wid;
  const int nw   = GEMM_BLOCKS * 4;
  const int m    = lane & 15;
  const int kq   = lane >> 4;

  FragU wf[8][4];
#pragma unroll
  for (int c = 0; c < 8; c++)
#pragma unroll
    for (int s = 0; s < 4; s++)
      wf[c][s].u = *((const ushort8*)(WP + (size_t)(((c * 4 + s) * 64 + lane) * 8)));

  uint32_t* Yu = (uint32_t*)Y;
  for (int t = gw; t < GEMM_TILES; t += nw){
    const int row0 = t * 16;
    FragU af[4];
#pragma unroll
    for (int s = 0; s < 4; s++)
      af[s].u = *((const ushort8*)(X + (size_t)(row0 + m) * HID + s * 32 + kq * 8));
    floatx4 acc[8];
#pragma unroll
    for (int c = 0; c < 8; c++) acc[c] = floatx4{0.f, 0.f, 0.f, 0.f};
#pragma unroll
    for (int s = 0; s < 4; s++)
#pragma unroll
      for (int c = 0; c < 8; c++)
        acc[c] = __builtin_amdgcn_mfma_f32_16x16x32_bf16(af[s].b, wf[c][s].b, acc[c], 0, 0, 0);
#pragma unroll
    for (int t4 = 0; t4 < 4; t4++)
#pragma unroll
      for (int i = 0; i < 4; i++){
        uint32_t pr = (uint32_t)f2bf(acc[2 * t4][i]) | ((uint32_t)f2bf(acc[2 * t4 + 1][i]) << 16);
        Yu[(size_t)(row0 + kq * 4 + i) * 64 + t4 * 16 + m] = pr;
      }
  }
}

// ---------- MFMA classifier: out = h @ WcS + cvec (fp32 out) ----------
__global__ __launch_bounds__(256) void k_cls_mfma(const uint16_t* __restrict__ H,
                                                  const uint16_t* __restrict__ WPC,
                                                  const float* __restrict__ cvec,
                                                  float* __restrict__ out){
  const int lane = threadIdx.x & 63;
  const int wid  = threadIdx.x >> 6;
  const int gw   = blockIdx.x * 4 + wid;
  const int nw   = GEMM_BLOCKS * 4;
  const int m    = lane & 15;
  const int kq   = lane >> 4;

  FragU wf[4];
#pragma unroll
  for (int s = 0; s < 4; s++)
    wf[s].u = *((const ushort8*)(WPC + (size_t)((s * 64 + lane) * 8)));
  const float cv = cvec[m];

  for (int t = gw; t < GEMM_TILES; t += nw){
    const int row0 = t * 16;
    FragU af[4];
#pragma unroll
    for (int s = 0; s < 4; s++)
      af[s].u = *((const ushort8*)(H + (size_t)(row0 + m) * HID + s * 32 + kq * 8));
    floatx4 acc = floatx4{0.f, 0.f, 0.f, 0.f};
#pragma unroll
    for (int s = 0; s < 4; s++)
      acc = __builtin_amdgcn_mfma_f32_16x16x32_bf16(af[s].b, wf[s].b, acc, 0, 0, 0);
#pragma unroll
    for (int i = 0; i < 4; i++)
      out[(size_t)(row0 + kq * 4 + i) * OUTD + m] = acc[i] + cv;
  }
}

// ---------- aggregation: node per wave, both batches (16 gathers in flight),
// ---------- next-node prefetch hides per-node serial latency ----------
__global__ __launch_bounds__(256) void k_agg(const uint16_t* __restrict__ XW,
                                             const int* __restrict__ rp,
                                             const unsigned long long* __restrict__ edg,
                                             const float* __restrict__ dinv,
                                             const float* __restrict__ bias,
                                             const float* __restrict__ cvec,
                                             uint16_t* __restrict__ H,
                                             float* __restrict__ psum,
                                             float* __restrict__ pssq){
  __shared__ float lsum[128];
  __shared__ float lssq[128];
  const int tid = threadIdx.x;
  if (tid < 128){ lsum[tid] = 0.f; lssq[tid] = 0.f; }
  __syncthreads();

  const int lane = tid & 63;
  const int wid  = tid >> 6;
  const int gw   = blockIdx.x * 4 + wid;
  const int nw   = AGG_BLOCKS * 4;
  const uint32_t* Xu = (const uint32_t*)XW;   // planar: row = 64 packed bf16x2
  uint32_t* Hu = (uint32_t*)H;
  const int f0 = lane * 2;
  const float b0 = bias[f0], b1 = bias[f0 + 1];
  const float c0 = cvec ? cvec[f0] : 0.f;
  const float c1 = cvec ? cvec[f0 + 1] : 0.f;
  float ts0 = 0.f, ts1 = 0.f, tq0 = 0.f, tq1 = 0.f;

  int node = gw;
  if (node < N_NODES){
    int e0 = rp[node], e1 = rp[node + 1];
    float di = dinv[node];
    uint32_t s0 = Xu[(size_t)node * 64 + lane];
    uint32_t s1 = Xu[(size_t)(N_NODES + node) * 64 + lane];
    while (true){
      // prefetch next node's header while this node's edges stream
      const int nn = node + nw;
      const bool more = (nn < N_NODES);
      int ne0 = 0, ne1 = 0; float ndi = 0.f; uint32_t ns0 = 0, ns1 = 0;
      if (more){
        ne0 = rp[nn]; ne1 = rp[nn + 1];
        ndi = dinv[nn];
        ns0 = Xu[(size_t)nn * 64 + lane];
        ns1 = Xu[(size_t)(N_NODES + nn) * 64 + lane];
      }

      const float sn = di * di;
      float a0x = sn * bf_lo(s0), a0y = sn * bf_hi(s0);
      float a1x = sn * bf_lo(s1), a1y = sn * bf_hi(s1);
      float wsum = sn;
      int e = e0;
      // unroll x8: 8 packed edge recs -> 16 independent row gathers in flight
      for (; e + 8 <= e1; e += 8){
        unsigned long long rec[8];
#pragma unroll
        for (int u = 0; u < 8; u++) rec[u] = edg[e + u];
        uint32_t q0[8], q1[8];
#pragma unroll
        for (int u = 0; u < 8; u++){
          size_t src = (uint32_t)rec[u];
          q0[u] = Xu[src * 64 + lane];
          q1[u] = Xu[(N_NODES + src) * 64 + lane];
        }
#pragma unroll
        for (int u = 0; u < 8; u++){
          float w = __uint_as_float((uint32_t)(rec[u] >> 32));
          a0x = fmaf(w, bf_lo(q0[u]), a0x); a0y = fmaf(w, bf_hi(q0[u]), a0y);
          a1x = fmaf(w, bf_lo(q1[u]), a1x); a1y = fmaf(w, bf_hi(q1[u]), a1y);
          wsum += w;
        }
      }
      for (; e + 4 <= e1; e += 4){
        unsigned long long rec[4];
#pragma unroll
        for (int u = 0; u < 4; u++) rec[u] = edg[e + u];
        uint32_t q0[4], q1[4];
#pragma unroll
        for (int u = 0; u < 4; u++){
          size_t src = (uint32_t)rec[u];
          q0[u] = Xu[src * 64 + lane];
          q1[u] = Xu[(N_NODES + src) * 64 + lane];
        }
#pragma unroll
        for (int u = 0; u < 4; u++){
          float w = __uint_as_float((uint32_t)(rec[u] >> 32));
          a0x = fmaf(w, bf_lo(q0[u]), a0x); a0y = fmaf(w, bf_hi(q0[u]), a0y);
          a1x = fmaf(w, bf_lo(q1[u]), a1x); a1y = fmaf(w, bf_hi(q1[u]), a1y);
          wsum += w;
        }
      }
      for (; e + 2 <= e1; e += 2){
        unsigned long long ra = edg[e], rb = edg[e + 1];
        size_t sa = (uint32_t)ra, sb = (uint32_t)rb;
        uint32_t qa0 = Xu[sa * 64 + lane], qa1 = Xu[(N_NODES + sa) * 64 + lane];
        uint32_t qb0 = Xu[sb * 64 + lane], qb1 = Xu[(N_NODES + sb) * 64 + lane];
        float wa = __uint_as_float((uint32_t)(ra >> 32));
        float wb = __uint_as_float((uint32_t)(rb >> 32));
        a0x = fmaf(wa, bf_lo(qa0), a0x); a0y = fmaf(wa, bf_hi(qa0), a0y);
        a1x = fmaf(wa, bf_lo(qa1), a1x); a1y = fmaf(wa, bf_hi(qa1), a1y);
        a0x = fmaf(wb, bf_lo(qb0), a0x); a0y = fmaf(wb, bf_hi(qb0), a0y);
        a1x = fmaf(wb, bf_lo(qb1), a1x); a1y = fmaf(wb, bf_hi(qb1), a1y);
        wsum += wa + wb;
      }
      for (; e < e1; e++){
        unsigned long long rec = edg[e];
        size_t src = (uint32_t)rec;
        float w = __uint_as_float((uint32_t)(rec >> 32));
        uint32_t g0 = Xu[src * 64 + lane];
        uint32_t g1 = Xu[(N_NODES + src) * 64 + lane];
        a0x = fmaf(w, bf_lo(g0), a0x); a0y = fmaf(w, bf_hi(g0), a0y);
        a1x = fmaf(w, bf_lo(g1), a1x); a1y = fmaf(w, bf_hi(g1), a1y);
        wsum += w;
      }
      // rank-1 BN-fold term + bias + relu
      a0x = fmaxf(fmaf(wsum, c0, a0x) + b0, 0.f); a0y = fmaxf(fmaf(wsum, c1, a0y) + b1, 0.f);
      a1x = fmaxf(fmaf(wsum, c0, a1x) + b0, 0.f); a1y = fmaxf(fmaf(wsum, c1, a1y) + b1, 0.f);
      Hu[(size_t)node * 64 + lane]             = (uint32_t)f2bf(a0x) | ((uint32_t)f2bf(a0y) << 16);
      Hu[(size_t)(N_NODES + node) * 64 + lane] = (uint32_t)f2bf(a1x) | ((uint32_t)f2bf(a1y) << 16);
      ts0 += a0x + a1x; ts1 += a0y + a1y;
      tq0 += a0x * a0x + a1x * a1x; tq1 += a0y * a0y + a1y * a1y;

      if (!more) break;
      node = nn; e0 = ne0; e1 = ne1; di = ndi; s0 = ns0; s1 = ns1;
    }
  }

  atomicAdd(&lsum[f0],     ts0); atomicAdd(&lsum[f0 + 1], ts1);
  atomicAdd(&lssq[f0],     tq0); atomicAdd(&lssq[f0 + 1], tq1);
  __syncthreads();
  if (tid < 128){
    psum[(size_t)blockIdx.x * 128 + tid] = lsum[tid];
    pssq[(size_t)blockIdx.x * 128 + tid] = lssq[tid];
  }
}

// ---------- BN mid-reduction: 2048 partial rows -> 32 ----------
__global__ __launch_bounds__(256) void k_bnmid(const float* __restrict__ psum,
                                               const float* __restrict__ pssq,
                                               float* __restrict__ msum,
                                               float* __restrict__ mssq){
  __shared__ float ss[2][128];
  __shared__ float sq[2][128];
  const int tid = threadIdx.x;
  const int f  = tid & 127;
  const int sl = tid >> 7;
  const int rows_per = AGG_BLOCKS / MID_BLOCKS;  // 64
  const int base = blockIdx.x * rows_per;
  float s = 0.f, q = 0.f;
  for (int r = base + sl; r < base + rows_per; r += 2){
    s += psum[(size_t)r * 128 + f];
    q += pssq[(size_t)r * 128 + f];
  }
  ss[sl][f] = s; sq[sl][f] = q;
  __syncthreads();
  if (tid < 128){
    msum[(size_t)blockIdx.x * 128 + tid] = ss[0][tid] + ss[1][tid];
    mssq[(size_t)blockIdx.x * 128 + tid] = sq[0][tid] + sq[1][tid];
  }
}

// ---------- BN finalize preamble (redundant per block, replaces k_bnfin) ----------
__device__ __forceinline__ void bn_finalize_lds(const float* __restrict__ msum,
                                                const float* __restrict__ mssq,
                                                const float* __restrict__ gamma,
                                                const float* __restrict__ beta,
                                                float* ssc, float* ssh){
  const int tid = threadIdx.x;
  if (tid < 128){
    float S = 0.f, Q = 0.f;
#pragma unroll
    for (int b = 0; b < MID_BLOCKS; b++){
      S += msum[(size_t)b * 128 + tid];
      Q += mssq[(size_t)b * 128 + tid];
    }
    const float inv = 1.0f / (float)ROWS;
    float mu = S * inv;
    float var = fmaxf(Q * inv - mu * mu, 0.f);
    float rstd = 1.0f / sqrtf(var + 1e-5f);
    float sc = gamma[tid] * rstd;
    ssc[tid] = sc;
    ssh[tid] = fmaf(-mu, sc, beta[tid]);
  }
  __syncthreads();
}

// ---------- prep2: BN1-finalize + pack s1(.)W2 + C2 = t1 @ W2 (9 blocks) ----------
__global__ void k_prep2(const float* __restrict__ msum, const float* __restrict__ mssq,
                        const float* __restrict__ gamma, const float* __restrict__ beta,
                        const float* __restrict__ W2,
                        uint16_t* __restrict__ WP2, float* __restrict__ C2){
  __shared__ float ssc[128];
  __shared__ float ssh[128];
  bn_finalize_lds(msum, mssq, gamma, beta, ssc, ssh);
  if (blockIdx.x < 8){
    pack_w(blockIdx.x * 256 + threadIdx.x, W2, ssc, WP2);
  } else if (threadIdx.x < 128){
    const int j = threadIdx.x;
    float a = 0.f;
    for (int k = 0; k < HID; k++) a = fmaf(ssh[k], W2[(size_t)k * HID + j], a);
    C2[j] = a;
  }
}

// ---------- prepc: BN2-finalize + pack s2(.)Wc + CVC = t2 @ Wc + bc (2 blocks) ----------
__global__ void k_prepc(const float* __restrict__ msum, const float* __restrict__ mssq,
                        const float* __restrict__ gamma, const float* __restrict__ beta,
                        const float* __restrict__ Wc, const float* __restrict__ bc,
                        uint16_t* __restrict__ WPC, float* __restrict__ CVC){
  __shared__ float ssc[128];
  __shared__ float ssh[128];
  bn_finalize_lds(msum, mssq, gamma, beta, ssc, ssh);
  if (blockIdx.x == 0){
    // classifier pack: single c-tile, original col mapping
    int t = threadIdx.x;
    int L = t & 63;
    int s = t >> 6;
    int n = L & 15;
    int k0 = s * 32 + (L >> 4) * 8;
    ushort8 r;
#pragma unroll
    for (int j = 0; j < 8; j++)
      r[j] = f2bf(ssc[k0 + j] * Wc[(size_t)(k0 + j) * OUTD + n]);
    *((ushort8*)(WPC + (size_t)t * 8)) = r;
  } else if (threadIdx.x < OUTD){
    const int j = threadIdx.x;
    float a = bc[j];
    for (int k = 0; k < HID; k++) a = fmaf(ssh[k], Wc[(size_t)k * OUTD + j], a);
    CVC[j] = a;
  }
}

// ---------- launch ----------
extern "C" void kernel_launch(void* const* d_in, const int* in_sizes, int n_in,
                              void* d_out, int out_size, void* d_ws, size_t ws_size,
                              hipStream_t stream){
  const float* x   = (const float*)d_in[0];
  const int*   ei  = (const int*)d_in[1];
  const float* ewp = (const float*)d_in[2];
  const float* W1  = (const float*)d_in[3];
  const float* b1  = (const float*)d_in[4];
  const float* W2  = (const float*)d_in[5];
  const float* b2  = (const float*)d_in[6];
  const float* g1  = (const float*)d_in[7];
  const float* be1 = (const float*)d_in[8];
  const float* g2  = (const float*)d_in[9];
  const float* be2 = (const float*)d_in[10];
  const float* Wc  = (const float*)d_in[11];
  const float* bc  = (const float*)d_in[12];
  float* out = (float*)d_out;

  char* wsb = (char*)d_ws;
  size_t off = 0;
  auto give = [&](size_t bytes) -> void* {
    void* p = wsb + off;
    off = (off + bytes + 255) & ~(size_t)255;
    return p;
  };
  uint16_t* XW  = (uint16_t*)give((size_t)ROWS * 128 * 2);   // planar [b][node][feat]
  uint16_t* Hb  = (uint16_t*)give((size_t)ROWS * 128 * 2);   // planar
  unsigned long long* DC  = (unsigned long long*)give((size_t)N_NODES * 8);
  unsigned long long* EDG = (unsigned long long*)give((size_t)N_EDGES * 8);
  unsigned int* SLOT = (unsigned int*)give((size_t)N_EDGES * 4);
  float* DINV   = (float*)give((size_t)N_NODES * 4);
  int*   RP     = (int*)give((size_t)(N_NODES + 1) * 4);
  int*   BSUM   = (int*)give(1024);
  float* PSUM   = (float*)give((size_t)AGG_BLOCKS * 128 * 4);
  float* PSSQ   = (float*)give((size_t)AGG_BLOCKS * 128 * 4);
  float* MSUM   = (float*)give((size_t)MID_BLOCKS * 128 * 4);
  float* MSSQ   = (float*)give((size_t)MID_BLOCKS * 128 * 4);
  uint16_t* WP1 = (uint16_t*)give((size_t)HID * HID * 2);
  uint16_t* WP2 = (uint16_t*)give((size_t)HID * HID * 2);
  uint16_t* WPC = (uint16_t*)give((size_t)HID * OUTD * 2);
  float* C2     = (float*)give(512);
  float* CVC    = (float*)give(64);
  (void)ws_size; (void)n_in; (void)in_sizes; (void)out_size;

  // 1: zero DC + pack W1
  k_initpack<<<SCAN_BLOCKS + 8, 256, 0, stream>>>(DC, W1, WP1);
  // 2: fused edge atomics (+SLOT) and GEMM1 (overlap, 5:2)
  k_edge_gemm1<<<EG_BLOCKS, 256, 0, stream>>>(ei, ewp, DC, SLOT, x, WP1, XW);
  // 3-5: CSR build
  k_scan_bsum<<<SCAN_BLOCKS, 256, 0, stream>>>(DC, BSUM, DINV);
  k_scan_write<<<SCAN_BLOCKS, 256, 0, stream>>>(DC, BSUM, RP);
  k_fill<<<(N_EDGES + 255) / 256, 256, 0, stream>>>(ei, ewp, DINV, SLOT, RP, EDG);
  // layer 1 aggregation + BN stats
  k_agg<<<AGG_BLOCKS, 256, 0, stream>>>(XW, RP, EDG, DINV, b1, nullptr, Hb, PSUM, PSSQ);
  k_bnmid<<<MID_BLOCKS, 256, 0, stream>>>(PSUM, PSSQ, MSUM, MSSQ);
  // BN1-finalize + W2 pack + C2
  k_prep2<<<9, 256, 0, stream>>>(MSUM, MSSQ, g1, be1, W2, WP2, C2);
  // layer 2
  k_gemm2<<<GEMM_BLOCKS, 256, 0, stream>>>(Hb, WP2, XW);
  k_agg<<<AGG_BLOCKS, 256, 0, stream>>>(XW, RP, EDG, DINV, b2, C2, Hb, PSUM, PSSQ);
  k_bnmid<<<MID_BLOCKS, 256, 0, stream>>>(PSUM, PSSQ, MSUM, MSSQ);
  // BN2-finalize + Wc pack + CVC
  k_prepc<<<2, 256, 0, stream>>>(MSUM, MSSQ, g2, be2, Wc, bc, WPC, CVC);
  // classifier
  k_cls_mfma<<<GEMM_BLOCKS, 256, 0, stream>>>(Hb, WPC, CVC, out);
}

// Round 10
// 319.412 us; speedup vs baseline: 1.1548x; 1.1548x over previous
//
#include <hip/hip_runtime.h>
#include <hip/hip_bf16.h>
#include <cstdint>
#include <cstddef>

#define N_NODES 50000
#define N_EDGES 640000
#define ROWS    100000   // B * N_NODES
#define HID     128
#define OUTD    16
#define AGG_BLOCKS 2048
#define MID_BLOCKS 32
#define SCAN_BLOCKS 196  // ceil(50000/256)
#define GEMM_BLOCKS 512
#define GEMM_TILES  (ROWS / 16)   // 6250
#define EG_BLOCKS   3500          // fused edge(2500) + gemm1(1000), 5:2 interleave
#define EG_GEMM_WAVES 4000        // 1000 blocks * 4 waves

// ---------- types ----------
typedef __attribute__((ext_vector_type(8))) uint16_t ushort8;
typedef __attribute__((ext_vector_type(8))) __bf16   bf16x8;
typedef __attribute__((ext_vector_type(4))) float    floatx4;

union FragU { ushort8 u; bf16x8 b; };

// ---------- bf16 helpers ----------
__device__ __forceinline__ float bf_lo(uint32_t u){
  union { uint32_t u; float f; } c; c.u = u << 16; return c.f;
}
__device__ __forceinline__ float bf_hi(uint32_t u){
  union { uint32_t u; float f; } c; c.u = u & 0xffff0000u; return c.f;
}
__device__ __forceinline__ uint16_t f2bf(float f){
  union { float f; uint32_t u; } c; c.f = f;
  uint32_t u = c.u;
  uint32_t r = (u + 0x7fffu + ((u >> 16) & 1u)) >> 16;  // RNE
  return (uint16_t)r;
}

// ---------- W pack (paired-column B-frag mapping), shared by initpack/prep2 ----------
// c-tile c, in-tile col m -> actual col (c>>1)*32 + 2m + (c&1)  (adjacent-col acc pairs)
__device__ __forceinline__ void pack_w(int t, const float* __restrict__ W,
                                       const float* sca /*LDS or null*/,
                                       uint16_t* __restrict__ WP){
  int L = t & 63;
  int s = (t >> 6) & 3;
  int c = t >> 8;
  int n = (c >> 1) * 32 + 2 * (L & 15) + (c & 1);
  int k0 = s * 32 + (L >> 4) * 8;
  ushort8 r;
#pragma unroll
  for (int j = 0; j < 8; j++){
    float w = W[(size_t)(k0 + j) * HID + n];
    if (sca) w *= sca[k0 + j];
    r[j] = f2bf(w);
  }
  *((ushort8*)(WP + (size_t)t * 8)) = r;
}

// ---------- launch 1: zero DC + pack W1 ----------
__global__ void k_initpack(unsigned long long* __restrict__ dc,
                           const float* __restrict__ W1, uint16_t* __restrict__ WP1){
  int b = blockIdx.x;
  if (b < SCAN_BLOCKS){
    int i = b * 256 + threadIdx.x;
    if (i < N_NODES) dc[i] = 0ull;
  } else {
    pack_w((b - SCAN_BLOCKS) * 256 + threadIdx.x, W1, nullptr, WP1);
  }
}

// ---------- launch 2: fused edge-degree atomics + GEMM1 (independent, overlap; 5:2) ----------
// DC[i]: bits[63:44] = in-degree count, bits[43:0] = sum(w) in 2^20 fixed point.
// NOTE: launch_bounds min-waves MUST stay 2 — min 4 caps VGPR at 128 and spills wf[8][4] (r9: +100MB scratch traffic)
__global__ __launch_bounds__(256, 2) void k_edge_gemm1(const int* __restrict__ ei,
                                                       const float* __restrict__ ewp,
                                                       unsigned long long* __restrict__ dc,
                                                       unsigned int* __restrict__ slot,
                                                       const float* __restrict__ X,
                                                       const uint16_t* __restrict__ WP,
                                                       uint16_t* __restrict__ Y){
  const int b = blockIdx.x;
  const int g = b % 7;
  if (g < 5){
    // ---- edge part: block eb handles 256 edges ----
    const int eb = (b / 7) * 5 + g;              // 0..2499
    const int e = eb * 256 + threadIdx.x;        // < 640000 exactly
    float w = expf(ewp[e]);
    int c = ei[N_EDGES + e];
    unsigned long long inc = (1ull << 44) | (unsigned long long)(w * 1048576.0f + 0.5f);
    unsigned long long old = atomicAdd(&dc[c], inc);
    slot[e] = (unsigned int)(old >> 44);
    return;
  }
  // ---- gemm1 part: bf16(x) @ W1' -> XW planar ----
  const int lane = threadIdx.x & 63;
  const int wid  = threadIdx.x >> 6;
  const int gw   = ((b / 7) * 2 + (g - 5)) * 4 + wid;   // 0..3999
  const int m    = lane & 15;
  const int kq   = lane >> 4;

  FragU wf[8][4];
#pragma unroll
  for (int c = 0; c < 8; c++)
#pragma unroll
    for (int s = 0; s < 4; s++)
      wf[c][s].u = *((const ushort8*)(WP + (size_t)(((c * 4 + s) * 64 + lane) * 8)));

  uint32_t* Yu = (uint32_t*)Y;
  for (int t = gw; t < GEMM_TILES; t += EG_GEMM_WAVES){
    const int row0 = t * 16;
    FragU af[4];
#pragma unroll
    for (int s = 0; s < 4; s++){
      const float* p = X + (size_t)(row0 + m) * HID + s * 32 + kq * 8;
      floatx4 f0 = *((const floatx4*)p);
      floatx4 f1 = *((const floatx4*)(p + 4));
      ushort8 r;
#pragma unroll
      for (int j = 0; j < 4; j++){ r[j] = f2bf(f0[j]); r[j + 4] = f2bf(f1[j]); }
      af[s].u = r;
    }
    floatx4 acc[8];
#pragma unroll
    for (int c = 0; c < 8; c++) acc[c] = floatx4{0.f, 0.f, 0.f, 0.f};
#pragma unroll
    for (int s = 0; s < 4; s++)
#pragma unroll
      for (int c = 0; c < 8; c++)
        acc[c] = __builtin_amdgcn_mfma_f32_16x16x32_bf16(af[s].b, wf[c][s].b, acc[c], 0, 0, 0);
#pragma unroll
    for (int t4 = 0; t4 < 4; t4++)
#pragma unroll
      for (int i = 0; i < 4; i++){
        uint32_t pr = (uint32_t)f2bf(acc[2 * t4][i]) | ((uint32_t)f2bf(acc[2 * t4 + 1][i]) << 16);
        Yu[(size_t)(row0 + kq * 4 + i) * 64 + t4 * 16 + m] = pr;
      }
  }
}

// ---------- launch 3: unpack DC -> dinv, block-sum counts ----------
__global__ void k_scan_bsum(const unsigned long long* __restrict__ dc, int* __restrict__ bsum,
                            float* __restrict__ dinv){
  __shared__ int sd[256];
  int tid = threadIdx.x;
  int i = blockIdx.x * 256 + tid;
  int cnt = 0;
  if (i < N_NODES){
    unsigned long long v = dc[i];
    cnt = (int)(v >> 44);
    float deg = 1.0f + (float)((double)(v & ((1ull << 44) - 1)) * (1.0 / 1048576.0));
    dinv[i] = 1.0f / sqrtf(deg);
  }
  sd[tid] = cnt;
  __syncthreads();
  for (int off = 128; off > 0; off >>= 1){
    if (tid < off) sd[tid] += sd[tid + off];
    __syncthreads();
  }
  if (tid == 0) bsum[blockIdx.x] = sd[0];
}

// ---------- launch 4: fused block-offset reduce + intra-block scan -> rp ----------
__global__ void k_scan_write(const unsigned long long* __restrict__ dc, const int* __restrict__ bsum,
                             int* __restrict__ rp){
  __shared__ int sb[256];
  __shared__ int sd[256];
  int tid = threadIdx.x;
  sb[tid] = (tid < SCAN_BLOCKS && tid < blockIdx.x) ? bsum[tid] : 0;
  __syncthreads();
  for (int off = 128; off > 0; off >>= 1){
    if (tid < off) sb[tid] += sb[tid + off];
    __syncthreads();
  }
  const int base = sb[0];

  int i = blockIdx.x * 256 + tid;
  int v = (i < N_NODES) ? (int)(dc[i] >> 44) : 0;
  sd[tid] = v;
  __syncthreads();
  for (int off = 1; off < 256; off <<= 1){
    int t = (tid >= off) ? sd[tid - off] : 0;
    __syncthreads();
    sd[tid] += t;
    __syncthreads();
  }
  if (i < N_NODES) rp[i] = base + sd[tid] - v;
  if (blockIdx.x == 0 && tid == 0) rp[N_NODES] = N_EDGES;
}

// ---------- launch 5: fill CSR with packed record (norm<<32 | src); slot known -> NO atomic ----------
__global__ void k_fill(const int* __restrict__ ei, const float* __restrict__ ewp,
                       const float* __restrict__ dinv, const unsigned int* __restrict__ slot,
                       const int* __restrict__ rp, unsigned long long* __restrict__ edg){
  int e = blockIdx.x * 256 + threadIdx.x;
  if (e < N_EDGES){
    int r = ei[e];
    int c = ei[N_EDGES + e];
    float w = expf(ewp[e]);
    float nrm = dinv[r] * w * dinv[c];
    int p = rp[c] + (int)slot[e];
    edg[p] = ((unsigned long long)__float_as_uint(nrm) << 32) | (unsigned int)r;
  }
}

// ---------- standalone GEMM2: bf16 H @ W2' -> XW planar ----------
__global__ __launch_bounds__(256, 2) void k_gemm2(const uint16_t* __restrict__ X,
                                                  const uint16_t* __restrict__ WP,
                                                  uint16_t* __restrict__ Y){
  const int lane = threadIdx.x & 63;
  const int wid  = threadIdx.x >> 6;
  const int gw   = blockIdx.x * 4 + wid;
  const int nw   = GEMM_BLOCKS * 4;
  const int m    = lane & 15;
  const int kq   = lane >> 4;

  FragU wf[8][4];
#pragma unroll
  for (int c = 0; c < 8; c++)
#pragma unroll
    for (int s = 0; s < 4; s++)
      wf[c][s].u = *((const ushort8*)(WP + (size_t)(((c * 4 + s) * 64 + lane) * 8)));

  uint32_t* Yu = (uint32_t*)Y;
  for (int t = gw; t < GEMM_TILES; t += nw){
    const int row0 = t * 16;
    FragU af[4];
#pragma unroll
    for (int s = 0; s < 4; s++)
      af[s].u = *((const ushort8*)(X + (size_t)(row0 + m) * HID + s * 32 + kq * 8));
    floatx4 acc[8];
#pragma unroll
    for (int c = 0; c < 8; c++) acc[c] = floatx4{0.f, 0.f, 0.f, 0.f};
#pragma unroll
    for (int s = 0; s < 4; s++)
#pragma unroll
      for (int c = 0; c < 8; c++)
        acc[c] = __builtin_amdgcn_mfma_f32_16x16x32_bf16(af[s].b, wf[c][s].b, acc[c], 0, 0, 0);
#pragma unroll
    for (int t4 = 0; t4 < 4; t4++)
#pragma unroll
      for (int i = 0; i < 4; i++){
        uint32_t pr = (uint32_t)f2bf(acc[2 * t4][i]) | ((uint32_t)f2bf(acc[2 * t4 + 1][i]) << 16);
        Yu[(size_t)(row0 + kq * 4 + i) * 64 + t4 * 16 + m] = pr;
      }
  }
}

// ---------- MFMA classifier: out = h @ WcS + cvec (fp32 out) ----------
__global__ __launch_bounds__(256) void k_cls_mfma(const uint16_t* __restrict__ H,
                                                  const uint16_t* __restrict__ WPC,
                                                  const float* __restrict__ cvec,
                                                  float* __restrict__ out){
  const int lane = threadIdx.x & 63;
  const int wid  = threadIdx.x >> 6;
  const int gw   = blockIdx.x * 4 + wid;
  const int nw   = GEMM_BLOCKS * 4;
  const int m    = lane & 15;
  const int kq   = lane >> 4;

  FragU wf[4];
#pragma unroll
  for (int s = 0; s < 4; s++)
    wf[s].u = *((const ushort8*)(WPC + (size_t)((s * 64 + lane) * 8)));
  const float cv = cvec[m];

  for (int t = gw; t < GEMM_TILES; t += nw){
    const int row0 = t * 16;
    FragU af[4];
#pragma unroll
    for (int s = 0; s < 4; s++)
      af[s].u = *((const ushort8*)(H + (size_t)(row0 + m) * HID + s * 32 + kq * 8));
    floatx4 acc = floatx4{0.f, 0.f, 0.f, 0.f};
#pragma unroll
    for (int s = 0; s < 4; s++)
      acc = __builtin_amdgcn_mfma_f32_16x16x32_bf16(af[s].b, wf[s].b, acc, 0, 0, 0);
#pragma unroll
    for (int i = 0; i < 4; i++)
      out[(size_t)(row0 + kq * 4 + i) * OUTD + m] = acc[i] + cv;
  }
}

// ---------- aggregation: node per wave, both batches (16 gathers in flight),
// ---------- next-node prefetch hides per-node serial latency ----------
__global__ __launch_bounds__(256) void k_agg(const uint16_t* __restrict__ XW,
                                             const int* __restrict__ rp,
                                             const unsigned long long* __restrict__ edg,
                                             const float* __restrict__ dinv,
                                             const float* __restrict__ bias,
                                             const float* __restrict__ cvec,
                                             uint16_t* __restrict__ H,
                                             float* __restrict__ psum,
                                             float* __restrict__ pssq){
  __shared__ float lsum[128];
  __shared__ float lssq[128];
  const int tid = threadIdx.x;
  if (tid < 128){ lsum[tid] = 0.f; lssq[tid] = 0.f; }
  __syncthreads();

  const int lane = tid & 63;
  const int wid  = tid >> 6;
  const int gw   = blockIdx.x * 4 + wid;
  const int nw   = AGG_BLOCKS * 4;
  const uint32_t* Xu = (const uint32_t*)XW;   // planar: row = 64 packed bf16x2
  uint32_t* Hu = (uint32_t*)H;
  const int f0 = lane * 2;
  const float b0 = bias[f0], b1 = bias[f0 + 1];
  const float c0 = cvec ? cvec[f0] : 0.f;
  const float c1 = cvec ? cvec[f0 + 1] : 0.f;
  float ts0 = 0.f, ts1 = 0.f, tq0 = 0.f, tq1 = 0.f;

  int node = gw;
  if (node < N_NODES){
    int e0 = rp[node], e1 = rp[node + 1];
    float di = dinv[node];
    uint32_t s0 = Xu[(size_t)node * 64 + lane];
    uint32_t s1 = Xu[(size_t)(N_NODES + node) * 64 + lane];
    while (true){
      // prefetch next node's header while this node's edges stream
      const int nn = node + nw;
      const bool more = (nn < N_NODES);
      int ne0 = 0, ne1 = 0; float ndi = 0.f; uint32_t ns0 = 0, ns1 = 0;
      if (more){
        ne0 = rp[nn]; ne1 = rp[nn + 1];
        ndi = dinv[nn];
        ns0 = Xu[(size_t)nn * 64 + lane];
        ns1 = Xu[(size_t)(N_NODES + nn) * 64 + lane];
      }

      const float sn = di * di;
      float a0x = sn * bf_lo(s0), a0y = sn * bf_hi(s0);
      float a1x = sn * bf_lo(s1), a1y = sn * bf_hi(s1);
      float wsum = sn;
      int e = e0;
      // unroll x8: 8 packed edge recs -> 16 independent row gathers in flight
      for (; e + 8 <= e1; e += 8){
        unsigned long long rec[8];
#pragma unroll
        for (int u = 0; u < 8; u++) rec[u] = edg[e + u];
        uint32_t q0[8], q1[8];
#pragma unroll
        for (int u = 0; u < 8; u++){
          size_t src = (uint32_t)rec[u];
          q0[u] = Xu[src * 64 + lane];
          q1[u] = Xu[(N_NODES + src) * 64 + lane];
        }
#pragma unroll
        for (int u = 0; u < 8; u++){
          float w = __uint_as_float((uint32_t)(rec[u] >> 32));
          a0x = fmaf(w, bf_lo(q0[u]), a0x); a0y = fmaf(w, bf_hi(q0[u]), a0y);
          a1x = fmaf(w, bf_lo(q1[u]), a1x); a1y = fmaf(w, bf_hi(q1[u]), a1y);
          wsum += w;
        }
      }
      for (; e + 4 <= e1; e += 4){
        unsigned long long rec[4];
#pragma unroll
        for (int u = 0; u < 4; u++) rec[u] = edg[e + u];
        uint32_t q0[4], q1[4];
#pragma unroll
        for (int u = 0; u < 4; u++){
          size_t src = (uint32_t)rec[u];
          q0[u] = Xu[src * 64 + lane];
          q1[u] = Xu[(N_NODES + src) * 64 + lane];
        }
#pragma unroll
        for (int u = 0; u < 4; u++){
          float w = __uint_as_float((uint32_t)(rec[u] >> 32));
          a0x = fmaf(w, bf_lo(q0[u]), a0x); a0y = fmaf(w, bf_hi(q0[u]), a0y);
          a1x = fmaf(w, bf_lo(q1[u]), a1x); a1y = fmaf(w, bf_hi(q1[u]), a1y);
          wsum += w;
        }
      }
      for (; e + 2 <= e1; e += 2){
        unsigned long long ra = edg[e], rb = edg[e + 1];
        size_t sa = (uint32_t)ra, sb = (uint32_t)rb;
        uint32_t qa0 = Xu[sa * 64 + lane], qa1 = Xu[(N_NODES + sa) * 64 + lane];
        uint32_t qb0 = Xu[sb * 64 + lane], qb1 = Xu[(N_NODES + sb) * 64 + lane];
        float wa = __uint_as_float((uint32_t)(ra >> 32));
        float wb = __uint_as_float((uint32_t)(rb >> 32));
        a0x = fmaf(wa, bf_lo(qa0), a0x); a0y = fmaf(wa, bf_hi(qa0), a0y);
        a1x = fmaf(wa, bf_lo(qa1), a1x); a1y = fmaf(wa, bf_hi(qa1), a1y);
        a0x = fmaf(wb, bf_lo(qb0), a0x); a0y = fmaf(wb, bf_hi(qb0), a0y);
        a1x = fmaf(wb, bf_lo(qb1), a1x); a1y = fmaf(wb, bf_hi(qb1), a1y);
        wsum += wa + wb;
      }
      for (; e < e1; e++){
        unsigned long long rec = edg[e];
        size_t src = (uint32_t)rec;
        float w = __uint_as_float((uint32_t)(rec >> 32));
        uint32_t g0 = Xu[src * 64 + lane];
        uint32_t g1 = Xu[(N_NODES + src) * 64 + lane];
        a0x = fmaf(w, bf_lo(g0), a0x); a0y = fmaf(w, bf_hi(g0), a0y);
        a1x = fmaf(w, bf_lo(g1), a1x); a1y = fmaf(w, bf_hi(g1), a1y);
        wsum += w;
      }
      // rank-1 BN-fold term + bias + relu
      a0x = fmaxf(fmaf(wsum, c0, a0x) + b0, 0.f); a0y = fmaxf(fmaf(wsum, c1, a0y) + b1, 0.f);
      a1x = fmaxf(fmaf(wsum, c0, a1x) + b0, 0.f); a1y = fmaxf(fmaf(wsum, c1, a1y) + b1, 0.f);
      Hu[(size_t)node * 64 + lane]             = (uint32_t)f2bf(a0x) | ((uint32_t)f2bf(a0y) << 16);
      Hu[(size_t)(N_NODES + node) * 64 + lane] = (uint32_t)f2bf(a1x) | ((uint32_t)f2bf(a1y) << 16);
      ts0 += a0x + a1x; ts1 += a0y + a1y;
      tq0 += a0x * a0x + a1x * a1x; tq1 += a0y * a0y + a1y * a1y;

      if (!more) break;
      node = nn; e0 = ne0; e1 = ne1; di = ndi; s0 = ns0; s1 = ns1;
    }
  }

  atomicAdd(&lsum[f0],     ts0); atomicAdd(&lsum[f0 + 1], ts1);
  atomicAdd(&lssq[f0],     tq0); atomicAdd(&lssq[f0 + 1], tq1);
  __syncthreads();
  if (tid < 128){
    psum[(size_t)blockIdx.x * 128 + tid] = lsum[tid];
    pssq[(size_t)blockIdx.x * 128 + tid] = lssq[tid];
  }
}

// ---------- BN mid-reduction: 2048 partial rows -> 32 ----------
__global__ __launch_bounds__(256) void k_bnmid(const float* __restrict__ psum,
                                               const float* __restrict__ pssq,
                                               float* __restrict__ msum,
                                               float* __restrict__ mssq){
  __shared__ float ss[2][128];
  __shared__ float sq[2][128];
  const int tid = threadIdx.x;
  const int f  = tid & 127;
  const int sl = tid >> 7;
  const int rows_per = AGG_BLOCKS / MID_BLOCKS;  // 64
  const int base = blockIdx.x * rows_per;
  float s = 0.f, q = 0.f;
  for (int r = base + sl; r < base + rows_per; r += 2){
    s += psum[(size_t)r * 128 + f];
    q += pssq[(size_t)r * 128 + f];
  }
  ss[sl][f] = s; sq[sl][f] = q;
  __syncthreads();
  if (tid < 128){
    msum[(size_t)blockIdx.x * 128 + tid] = ss[0][tid] + ss[1][tid];
    mssq[(size_t)blockIdx.x * 128 + tid] = sq[0][tid] + sq[1][tid];
  }
}

// ---------- BN finalize preamble (redundant per block, replaces k_bnfin) ----------
__device__ __forceinline__ void bn_finalize_lds(const float* __restrict__ msum,
                                                const float* __restrict__ mssq,
                                                const float* __restrict__ gamma,
                                                const float* __restrict__ beta,
                                                float* ssc, float* ssh){
  const int tid = threadIdx.x;
  if (tid < 128){
    float S = 0.f, Q = 0.f;
#pragma unroll
    for (int b = 0; b < MID_BLOCKS; b++){
      S += msum[(size_t)b * 128 + tid];
      Q += mssq[(size_t)b * 128 + tid];
    }
    const float inv = 1.0f / (float)ROWS;
    float mu = S * inv;
    float var = fmaxf(Q * inv - mu * mu, 0.f);
    float rstd = 1.0f / sqrtf(var + 1e-5f);
    float sc = gamma[tid] * rstd;
    ssc[tid] = sc;
    ssh[tid] = fmaf(-mu, sc, beta[tid]);
  }
  __syncthreads();
}

// ---------- prep2: BN1-finalize + pack s1(.)W2 + C2 = t1 @ W2 (9 blocks) ----------
__global__ void k_prep2(const float* __restrict__ msum, const float* __restrict__ mssq,
                        const float* __restrict__ gamma, const float* __restrict__ beta,
                        const float* __restrict__ W2,
                        uint16_t* __restrict__ WP2, float* __restrict__ C2){
  __shared__ float ssc[128];
  __shared__ float ssh[128];
  bn_finalize_lds(msum, mssq, gamma, beta, ssc, ssh);
  if (blockIdx.x < 8){
    pack_w(blockIdx.x * 256 + threadIdx.x, W2, ssc, WP2);
  } else if (threadIdx.x < 128){
    const int j = threadIdx.x;
    float a = 0.f;
    for (int k = 0; k < HID; k++) a = fmaf(ssh[k], W2[(size_t)k * HID + j], a);
    C2[j] = a;
  }
}

// ---------- prepc: BN2-finalize + pack s2(.)Wc + CVC = t2 @ Wc + bc (2 blocks) ----------
__global__ void k_prepc(const float* __restrict__ msum, const float* __restrict__ mssq,
                        const float* __restrict__ gamma, const float* __restrict__ beta,
                        const float* __restrict__ Wc, const float* __restrict__ bc,
                        uint16_t* __restrict__ WPC, float* __restrict__ CVC){
  __shared__ float ssc[128];
  __shared__ float ssh[128];
  bn_finalize_lds(msum, mssq, gamma, beta, ssc, ssh);
  if (blockIdx.x == 0){
    // classifier pack: single c-tile, original col mapping
    int t = threadIdx.x;
    int L = t & 63;
    int s = t >> 6;
    int n = L & 15;
    int k0 = s * 32 + (L >> 4) * 8;
    ushort8 r;
#pragma unroll
    for (int j = 0; j < 8; j++)
      r[j] = f2bf(ssc[k0 + j] * Wc[(size_t)(k0 + j) * OUTD + n]);
    *((ushort8*)(WPC + (size_t)t * 8)) = r;
  } else if (threadIdx.x < OUTD){
    const int j = threadIdx.x;
    float a = bc[j];
    for (int k = 0; k < HID; k++) a = fmaf(ssh[k], Wc[(size_t)k * OUTD + j], a);
    CVC[j] = a;
  }
}

// ---------- launch ----------
extern "C" void kernel_launch(void* const* d_in, const int* in_sizes, int n_in,
                              void* d_out, int out_size, void* d_ws, size_t ws_size,
                              hipStream_t stream){
  const float* x   = (const float*)d_in[0];
  const int*   ei  = (const int*)d_in[1];
  const float* ewp = (const float*)d_in[2];
  const float* W1  = (const float*)d_in[3];
  const float* b1  = (const float*)d_in[4];
  const float* W2  = (const float*)d_in[5];
  const float* b2  = (const float*)d_in[6];
  const float* g1  = (const float*)d_in[7];
  const float* be1 = (const float*)d_in[8];
  const float* g2  = (const float*)d_in[9];
  const float* be2 = (const float*)d_in[10];
  const float* Wc  = (const float*)d_in[11];
  const float* bc  = (const float*)d_in[12];
  float* out = (float*)d_out;

  char* wsb = (char*)d_ws;
  size_t off = 0;
  auto give = [&](size_t bytes) -> void* {
    void* p = wsb + off;
    off = (off + bytes + 255) & ~(size_t)255;
    return p;
  };
  uint16_t* XW  = (uint16_t*)give((size_t)ROWS * 128 * 2);   // planar [b][node][feat]
  uint16_t* Hb  = (uint16_t*)give((size_t)ROWS * 128 * 2);   // planar
  unsigned long long* DC  = (unsigned long long*)give((size_t)N_NODES * 8);
  unsigned long long* EDG = (unsigned long long*)give((size_t)N_EDGES * 8);
  unsigned int* SLOT = (unsigned int*)give((size_t)N_EDGES * 4);
  float* DINV   = (float*)give((size_t)N_NODES * 4);
  int*   RP     = (int*)give((size_t)(N_NODES + 1) * 4);
  int*   BSUM   = (int*)give(1024);
  float* PSUM   = (float*)give((size_t)AGG_BLOCKS * 128 * 4);
  float* PSSQ   = (float*)give((size_t)AGG_BLOCKS * 128 * 4);
  float* MSUM   = (float*)give((size_t)MID_BLOCKS * 128 * 4);
  float* MSSQ   = (float*)give((size_t)MID_BLOCKS * 128 * 4);
  uint16_t* WP1 = (uint16_t*)give((size_t)HID * HID * 2);
  uint16_t* WP2 = (uint16_t*)give((size_t)HID * HID * 2);
  uint16_t* WPC = (uint16_t*)give((size_t)HID * OUTD * 2);
  float* C2     = (float*)give(512);
  float* CVC    = (float*)give(64);
  (void)ws_size; (void)n_in; (void)in_sizes; (void)out_size;

  // 1: zero DC + pack W1
  k_initpack<<<SCAN_BLOCKS + 8, 256, 0, stream>>>(DC, W1, WP1);
  // 2: fused edge atomics (+SLOT) and GEMM1 (overlap, 5:2, NO reg cap)
  k_edge_gemm1<<<EG_BLOCKS, 256, 0, stream>>>(ei, ewp, DC, SLOT, x, WP1, XW);
  // 3-5: CSR build
  k_scan_bsum<<<SCAN_BLOCKS, 256, 0, stream>>>(DC, BSUM, DINV);
  k_scan_write<<<SCAN_BLOCKS, 256, 0, stream>>>(DC, BSUM, RP);
  k_fill<<<(N_EDGES + 255) / 256, 256, 0, stream>>>(ei, ewp, DINV, SLOT, RP, EDG);
  // layer 1 aggregation + BN stats
  k_agg<<<AGG_BLOCKS, 256, 0, stream>>>(XW, RP, EDG, DINV, b1, nullptr, Hb, PSUM, PSSQ);
  k_bnmid<<<MID_BLOCKS, 256, 0, stream>>>(PSUM, PSSQ, MSUM, MSSQ);
  // BN1-finalize + W2 pack + C2
  k_prep2<<<9, 256, 0, stream>>>(MSUM, MSSQ, g1, be1, W2, WP2, C2);
  // layer 2
  k_gemm2<<<GEMM_BLOCKS, 256, 0, stream>>>(Hb, WP2, XW);
  k_agg<<<AGG_BLOCKS, 256, 0, stream>>>(XW, RP, EDG, DINV, b2, C2, Hb, PSUM, PSSQ);
  k_bnmid<<<MID_BLOCKS, 256, 0, stream>>>(PSUM, PSSQ, MSUM, MSSQ);
  // BN2-finalize + Wc pack + CVC
  k_prepc<<<2, 256, 0, stream>>>(MSUM, MSSQ, g2, be2, Wc, bc, WPC, CVC);
  // classifier
  k_cls_mfma<<<GEMM_BLOCKS, 256, 0, stream>>>(Hb, WPC, CVC, out);
}

// Round 11
// 316.092 us; speedup vs baseline: 1.1669x; 1.0105x over previous
//
#include <hip/hip_runtime.h>
#include <hip/hip_bf16.h>
#include <cstdint>
#include <cstddef>

#define N_NODES 50000
#define N_EDGES 640000
#define ROWS    100000   // B * N_NODES
#define HID     128
#define OUTD    16
#define AGG_BLOCKS 2048
#define MID_BLOCKS 32
#define SCAN_BLOCKS 196  // ceil(50000/256)
#define GEMM_BLOCKS 512
#define GEMM_TILES  (ROWS / 16)   // 6250
#define EG_BLOCKS   3500          // fused edge(2500) + gemm1(1000), 5:2 interleave
#define EG_GEMM_WAVES 4000        // 1000 blocks * 4 waves

// ---------- types ----------
typedef __attribute__((ext_vector_type(8))) uint16_t ushort8;
typedef __attribute__((ext_vector_type(8))) __bf16   bf16x8;
typedef __attribute__((ext_vector_type(4))) float    floatx4;

union FragU { ushort8 u; bf16x8 b; };

// ---------- bf16 helpers ----------
__device__ __forceinline__ float bf_lo(uint32_t u){
  union { uint32_t u; float f; } c; c.u = u << 16; return c.f;
}
__device__ __forceinline__ float bf_hi(uint32_t u){
  union { uint32_t u; float f; } c; c.u = u & 0xffff0000u; return c.f;
}
__device__ __forceinline__ uint16_t f2bf(float f){
  union { float f; uint32_t u; } c; c.f = f;
  uint32_t u = c.u;
  uint32_t r = (u + 0x7fffu + ((u >> 16) & 1u)) >> 16;  // RNE
  return (uint16_t)r;
}

// ---------- W pack (paired-column B-frag mapping), shared by initpack/prep2 ----------
// c-tile c, in-tile col m -> actual col (c>>1)*32 + 2m + (c&1)  (adjacent-col acc pairs)
__device__ __forceinline__ void pack_w(int t, const float* __restrict__ W,
                                       const float* sca /*LDS or null*/,
                                       uint16_t* __restrict__ WP){
  int L = t & 63;
  int s = (t >> 6) & 3;
  int c = t >> 8;
  int n = (c >> 1) * 32 + 2 * (L & 15) + (c & 1);
  int k0 = s * 32 + (L >> 4) * 8;
  ushort8 r;
#pragma unroll
  for (int j = 0; j < 8; j++){
    float w = W[(size_t)(k0 + j) * HID + n];
    if (sca) w *= sca[k0 + j];
    r[j] = f2bf(w);
  }
  *((ushort8*)(WP + (size_t)t * 8)) = r;
}

// ---------- launch 1: zero DC + pack W1 ----------
__global__ void k_initpack(unsigned long long* __restrict__ dc,
                           const float* __restrict__ W1, uint16_t* __restrict__ WP1){
  int b = blockIdx.x;
  if (b < SCAN_BLOCKS){
    int i = b * 256 + threadIdx.x;
    if (i < N_NODES) dc[i] = 0ull;
  } else {
    pack_w((b - SCAN_BLOCKS) * 256 + threadIdx.x, W1, nullptr, WP1);
  }
}

// ---------- launch 2: fused edge-degree atomics + GEMM1 (independent, overlap; 5:2) ----------
// DC[i]: bits[63:44] = in-degree count, bits[43:0] = sum(w) in 2^20 fixed point.
// NOTE: launch_bounds min-waves MUST stay 2 — min 4 caps VGPR at 128 and spills wf[8][4] (r9: +100MB scratch traffic)
__global__ __launch_bounds__(256, 2) void k_edge_gemm1(const int* __restrict__ ei,
                                                       const float* __restrict__ ewp,
                                                       unsigned long long* __restrict__ dc,
                                                       unsigned int* __restrict__ slot,
                                                       const float* __restrict__ X,
                                                       const uint16_t* __restrict__ WP,
                                                       uint16_t* __restrict__ Y){
  const int b = blockIdx.x;
  const int g = b % 7;
  if (g < 5){
    // ---- edge part: block eb handles 256 edges ----
    const int eb = (b / 7) * 5 + g;              // 0..2499
    const int e = eb * 256 + threadIdx.x;        // < 640000 exactly
    float w = expf(ewp[e]);
    int c = ei[N_EDGES + e];
    unsigned long long inc = (1ull << 44) | (unsigned long long)(w * 1048576.0f + 0.5f);
    unsigned long long old = atomicAdd(&dc[c], inc);
    slot[e] = (unsigned int)(old >> 44);
    return;
  }
  // ---- gemm1 part: bf16(x) @ W1' -> XW planar ----
  const int lane = threadIdx.x & 63;
  const int wid  = threadIdx.x >> 6;
  const int gw   = ((b / 7) * 2 + (g - 5)) * 4 + wid;   // 0..3999
  const int m    = lane & 15;
  const int kq   = lane >> 4;

  FragU wf[8][4];
#pragma unroll
  for (int c = 0; c < 8; c++)
#pragma unroll
    for (int s = 0; s < 4; s++)
      wf[c][s].u = *((const ushort8*)(WP + (size_t)(((c * 4 + s) * 64 + lane) * 8)));

  uint32_t* Yu = (uint32_t*)Y;
  for (int t = gw; t < GEMM_TILES; t += EG_GEMM_WAVES){
    const int row0 = t * 16;
    FragU af[4];
#pragma unroll
    for (int s = 0; s < 4; s++){
      const float* p = X + (size_t)(row0 + m) * HID + s * 32 + kq * 8;
      floatx4 f0 = *((const floatx4*)p);
      floatx4 f1 = *((const floatx4*)(p + 4));
      ushort8 r;
#pragma unroll
      for (int j = 0; j < 4; j++){ r[j] = f2bf(f0[j]); r[j + 4] = f2bf(f1[j]); }
      af[s].u = r;
    }
    floatx4 acc[8];
#pragma unroll
    for (int c = 0; c < 8; c++) acc[c] = floatx4{0.f, 0.f, 0.f, 0.f};
#pragma unroll
    for (int s = 0; s < 4; s++)
#pragma unroll
      for (int c = 0; c < 8; c++)
        acc[c] = __builtin_amdgcn_mfma_f32_16x16x32_bf16(af[s].b, wf[c][s].b, acc[c], 0, 0, 0);
#pragma unroll
    for (int t4 = 0; t4 < 4; t4++)
#pragma unroll
      for (int i = 0; i < 4; i++){
        uint32_t pr = (uint32_t)f2bf(acc[2 * t4][i]) | ((uint32_t)f2bf(acc[2 * t4 + 1][i]) << 16);
        Yu[(size_t)(row0 + kq * 4 + i) * 64 + t4 * 16 + m] = pr;
      }
  }
}

// ---------- launch 3: unpack DC -> dinv, block-sum counts ----------
__global__ void k_scan_bsum(const unsigned long long* __restrict__ dc, int* __restrict__ bsum,
                            float* __restrict__ dinv){
  __shared__ int sd[256];
  int tid = threadIdx.x;
  int i = blockIdx.x * 256 + tid;
  int cnt = 0;
  if (i < N_NODES){
    unsigned long long v = dc[i];
    cnt = (int)(v >> 44);
    float deg = 1.0f + (float)((double)(v & ((1ull << 44) - 1)) * (1.0 / 1048576.0));
    dinv[i] = 1.0f / sqrtf(deg);
  }
  sd[tid] = cnt;
  __syncthreads();
  for (int off = 128; off > 0; off >>= 1){
    if (tid < off) sd[tid] += sd[tid + off];
    __syncthreads();
  }
  if (tid == 0) bsum[blockIdx.x] = sd[0];
}

// ---------- launch 4: fused block-offset reduce + intra-block scan -> rp ----------
__global__ void k_scan_write(const unsigned long long* __restrict__ dc, const int* __restrict__ bsum,
                             int* __restrict__ rp){
  __shared__ int sb[256];
  __shared__ int sd[256];
  int tid = threadIdx.x;
  sb[tid] = (tid < SCAN_BLOCKS && tid < blockIdx.x) ? bsum[tid] : 0;
  __syncthreads();
  for (int off = 128; off > 0; off >>= 1){
    if (tid < off) sb[tid] += sb[tid + off];
    __syncthreads();
  }
  const int base = sb[0];

  int i = blockIdx.x * 256 + tid;
  int v = (i < N_NODES) ? (int)(dc[i] >> 44) : 0;
  sd[tid] = v;
  __syncthreads();
  for (int off = 1; off < 256; off <<= 1){
    int t = (tid >= off) ? sd[tid - off] : 0;
    __syncthreads();
    sd[tid] += t;
    __syncthreads();
  }
  if (i < N_NODES) rp[i] = base + sd[tid] - v;
  if (blockIdx.x == 0 && tid == 0) rp[N_NODES] = N_EDGES;
}

// ---------- launch 5: fill CSR with packed record (norm<<32 | src); slot known -> NO atomic ----------
__global__ void k_fill(const int* __restrict__ ei, const float* __restrict__ ewp,
                       const float* __restrict__ dinv, const unsigned int* __restrict__ slot,
                       const int* __restrict__ rp, unsigned long long* __restrict__ edg){
  int e = blockIdx.x * 256 + threadIdx.x;
  if (e < N_EDGES){
    int r = ei[e];
    int c = ei[N_EDGES + e];
    float w = expf(ewp[e]);
    float nrm = dinv[r] * w * dinv[c];
    int p = rp[c] + (int)slot[e];
    edg[p] = ((unsigned long long)__float_as_uint(nrm) << 32) | (unsigned int)r;
  }
}

// ---------- standalone GEMM2: bf16 H @ W2' -> XW planar ----------
__global__ __launch_bounds__(256, 2) void k_gemm2(const uint16_t* __restrict__ X,
                                                  const uint16_t* __restrict__ WP,
                                                  uint16_t* __restrict__ Y){
  const int lane = threadIdx.x & 63;
  const int wid  = threadIdx.x >> 6;
  const int gw   = blockIdx.x * 4 + wid;
  const int nw   = GEMM_BLOCKS * 4;
  const int m    = lane & 15;
  const int kq   = lane >> 4;

  FragU wf[8][4];
#pragma unroll
  for (int c = 0; c < 8; c++)
#pragma unroll
    for (int s = 0; s < 4; s++)
      wf[c][s].u = *((const ushort8*)(WP + (size_t)(((c * 4 + s) * 64 + lane) * 8)));

  uint32_t* Yu = (uint32_t*)Y;
  for (int t = gw; t < GEMM_TILES; t += nw){
    const int row0 = t * 16;
    FragU af[4];
#pragma unroll
    for (int s = 0; s < 4; s++)
      af[s].u = *((const ushort8*)(X + (size_t)(row0 + m) * HID + s * 32 + kq * 8));
    floatx4 acc[8];
#pragma unroll
    for (int c = 0; c < 8; c++) acc[c] = floatx4{0.f, 0.f, 0.f, 0.f};
#pragma unroll
    for (int s = 0; s < 4; s++)
#pragma unroll
      for (int c = 0; c < 8; c++)
        acc[c] = __builtin_amdgcn_mfma_f32_16x16x32_bf16(af[s].b, wf[c][s].b, acc[c], 0, 0, 0);
#pragma unroll
    for (int t4 = 0; t4 < 4; t4++)
#pragma unroll
      for (int i = 0; i < 4; i++){
        uint32_t pr = (uint32_t)f2bf(acc[2 * t4][i]) | ((uint32_t)f2bf(acc[2 * t4 + 1][i]) << 16);
        Yu[(size_t)(row0 + kq * 4 + i) * 64 + t4 * 16 + m] = pr;
      }
  }
}

// ---------- MFMA classifier: out = h @ WcS + cvec (fp32 out) ----------
__global__ __launch_bounds__(256) void k_cls_mfma(const uint16_t* __restrict__ H,
                                                  const uint16_t* __restrict__ WPC,
                                                  const float* __restrict__ cvec,
                                                  float* __restrict__ out){
  const int lane = threadIdx.x & 63;
  const int wid  = threadIdx.x >> 6;
  const int gw   = blockIdx.x * 4 + wid;
  const int nw   = GEMM_BLOCKS * 4;
  const int m    = lane & 15;
  const int kq   = lane >> 4;

  FragU wf[4];
#pragma unroll
  for (int s = 0; s < 4; s++)
    wf[s].u = *((const ushort8*)(WPC + (size_t)((s * 64 + lane) * 8)));
  const float cv = cvec[m];

  for (int t = gw; t < GEMM_TILES; t += nw){
    const int row0 = t * 16;
    FragU af[4];
#pragma unroll
    for (int s = 0; s < 4; s++)
      af[s].u = *((const ushort8*)(H + (size_t)(row0 + m) * HID + s * 32 + kq * 8));
    floatx4 acc = floatx4{0.f, 0.f, 0.f, 0.f};
#pragma unroll
    for (int s = 0; s < 4; s++)
      acc = __builtin_amdgcn_mfma_f32_16x16x32_bf16(af[s].b, wf[s].b, acc, 0, 0, 0);
#pragma unroll
    for (int i = 0; i < 4; i++)
      out[(size_t)(row0 + kq * 4 + i) * OUTD + m] = acc[i] + cv;
  }
}

// ---------- aggregation: node per wave, both batches (16 gathers in flight),
// edge records loaded LATERALLY (lane u holds rec[e+u]) + readlane broadcast:
// 1 coalesced VMEM replaces 8 wave-uniform broadcast loads; src/w become SGPRs ----------
__global__ __launch_bounds__(256) void k_agg(const uint16_t* __restrict__ XW,
                                             const int* __restrict__ rp,
                                             const unsigned long long* __restrict__ edg,
                                             const float* __restrict__ dinv,
                                             const float* __restrict__ bias,
                                             const float* __restrict__ cvec,
                                             uint16_t* __restrict__ H,
                                             float* __restrict__ psum,
                                             float* __restrict__ pssq){
  __shared__ float lsum[128];
  __shared__ float lssq[128];
  const int tid = threadIdx.x;
  if (tid < 128){ lsum[tid] = 0.f; lssq[tid] = 0.f; }
  __syncthreads();

  const int lane = tid & 63;
  const int wid  = tid >> 6;
  const int gw   = blockIdx.x * 4 + wid;
  const int nw   = AGG_BLOCKS * 4;
  const uint32_t* Xu = (const uint32_t*)XW;   // planar: row = 64 packed bf16x2
  uint32_t* Hu = (uint32_t*)H;
  const int f0 = lane * 2;
  const float b0 = bias[f0], b1 = bias[f0 + 1];
  const float c0 = cvec ? cvec[f0] : 0.f;
  const float c1 = cvec ? cvec[f0 + 1] : 0.f;
  float ts0 = 0.f, ts1 = 0.f, tq0 = 0.f, tq1 = 0.f;

  int node = gw;
  if (node < N_NODES){
    int e0 = rp[node], e1 = rp[node + 1];
    float di = dinv[node];
    uint32_t s0 = Xu[(size_t)node * 64 + lane];
    uint32_t s1 = Xu[(size_t)(N_NODES + node) * 64 + lane];
    while (true){
      // prefetch next node's header while this node's edges stream
      const int nn = node + nw;
      const bool more = (nn < N_NODES);
      int ne0 = 0, ne1 = 0; float ndi = 0.f; uint32_t ns0 = 0, ns1 = 0;
      if (more){
        ne0 = rp[nn]; ne1 = rp[nn + 1];
        ndi = dinv[nn];
        ns0 = Xu[(size_t)nn * 64 + lane];
        ns1 = Xu[(size_t)(N_NODES + nn) * 64 + lane];
      }

      const float sn = di * di;
      float a0x = sn * bf_lo(s0), a0y = sn * bf_hi(s0);
      float a1x = sn * bf_lo(s1), a1y = sn * bf_hi(s1);
      float wsum = sn;
      int e = e0;
      // 8-edge groups: lateral rec load + readlane -> 16 gathers in flight, SGPR bases
      for (; e + 8 <= e1; e += 8){
        unsigned long long myrec = edg[e + (lane & 7)];
        uint32_t rlo = (uint32_t)myrec;
        uint32_t rhi = (uint32_t)(myrec >> 32);
        int srcs[8]; float ws[8];
#pragma unroll
        for (int u = 0; u < 8; u++){
          srcs[u] = __builtin_amdgcn_readlane(rlo, u);
          ws[u] = __uint_as_float((uint32_t)__builtin_amdgcn_readlane((int)rhi, u));
        }
        uint32_t q0[8], q1[8];
#pragma unroll
        for (int u = 0; u < 8; u++){
          q0[u] = Xu[(size_t)(uint32_t)srcs[u] * 64 + lane];
          q1[u] = Xu[(size_t)(N_NODES + (uint32_t)srcs[u]) * 64 + lane];
        }
#pragma unroll
        for (int u = 0; u < 8; u++){
          a0x = fmaf(ws[u], bf_lo(q0[u]), a0x); a0y = fmaf(ws[u], bf_hi(q0[u]), a0y);
          a1x = fmaf(ws[u], bf_lo(q1[u]), a1x); a1y = fmaf(ws[u], bf_hi(q1[u]), a1y);
          wsum += ws[u];
        }
      }
      // 4-edge group, same lateral trick
      for (; e + 4 <= e1; e += 4){
        unsigned long long myrec = edg[e + (lane & 3)];
        uint32_t rlo = (uint32_t)myrec;
        uint32_t rhi = (uint32_t)(myrec >> 32);
        int srcs[4]; float ws[4];
#pragma unroll
        for (int u = 0; u < 4; u++){
          srcs[u] = __builtin_amdgcn_readlane(rlo, u);
          ws[u] = __uint_as_float((uint32_t)__builtin_amdgcn_readlane((int)rhi, u));
        }
        uint32_t q0[4], q1[4];
#pragma unroll
        for (int u = 0; u < 4; u++){
          q0[u] = Xu[(size_t)(uint32_t)srcs[u] * 64 + lane];
          q1[u] = Xu[(size_t)(N_NODES + (uint32_t)srcs[u]) * 64 + lane];
        }
#pragma unroll
        for (int u = 0; u < 4; u++){
          a0x = fmaf(ws[u], bf_lo(q0[u]), a0x); a0y = fmaf(ws[u], bf_hi(q0[u]), a0y);
          a1x = fmaf(ws[u], bf_lo(q1[u]), a1x); a1y = fmaf(ws[u], bf_hi(q1[u]), a1y);
          wsum += ws[u];
        }
      }
      for (; e < e1; e++){
        unsigned long long rec = edg[e];
        size_t src = (uint32_t)rec;
        float w = __uint_as_float((uint32_t)(rec >> 32));
        uint32_t g0 = Xu[src * 64 + lane];
        uint32_t g1 = Xu[(N_NODES + src) * 64 + lane];
        a0x = fmaf(w, bf_lo(g0), a0x); a0y = fmaf(w, bf_hi(g0), a0y);
        a1x = fmaf(w, bf_lo(g1), a1x); a1y = fmaf(w, bf_hi(g1), a1y);
        wsum += w;
      }
      // rank-1 BN-fold term + bias + relu
      a0x = fmaxf(fmaf(wsum, c0, a0x) + b0, 0.f); a0y = fmaxf(fmaf(wsum, c1, a0y) + b1, 0.f);
      a1x = fmaxf(fmaf(wsum, c0, a1x) + b0, 0.f); a1y = fmaxf(fmaf(wsum, c1, a1y) + b1, 0.f);
      Hu[(size_t)node * 64 + lane]             = (uint32_t)f2bf(a0x) | ((uint32_t)f2bf(a0y) << 16);
      Hu[(size_t)(N_NODES + node) * 64 + lane] = (uint32_t)f2bf(a1x) | ((uint32_t)f2bf(a1y) << 16);
      ts0 += a0x + a1x; ts1 += a0y + a1y;
      tq0 += a0x * a0x + a1x * a1x; tq1 += a0y * a0y + a1y * a1y;

      if (!more) break;
      node = nn; e0 = ne0; e1 = ne1; di = ndi; s0 = ns0; s1 = ns1;
    }
  }

  atomicAdd(&lsum[f0],     ts0); atomicAdd(&lsum[f0 + 1], ts1);
  atomicAdd(&lssq[f0],     tq0); atomicAdd(&lssq[f0 + 1], tq1);
  __syncthreads();
  if (tid < 128){
    psum[(size_t)blockIdx.x * 128 + tid] = lsum[tid];
    pssq[(size_t)blockIdx.x * 128 + tid] = lssq[tid];
  }
}

// ---------- BN mid-reduction: 2048 partial rows -> 32 ----------
__global__ __launch_bounds__(256) void k_bnmid(const float* __restrict__ psum,
                                               const float* __restrict__ pssq,
                                               float* __restrict__ msum,
                                               float* __restrict__ mssq){
  __shared__ float ss[2][128];
  __shared__ float sq[2][128];
  const int tid = threadIdx.x;
  const int f  = tid & 127;
  const int sl = tid >> 7;
  const int rows_per = AGG_BLOCKS / MID_BLOCKS;  // 64
  const int base = blockIdx.x * rows_per;
  float s = 0.f, q = 0.f;
  for (int r = base + sl; r < base + rows_per; r += 2){
    s += psum[(size_t)r * 128 + f];
    q += pssq[(size_t)r * 128 + f];
  }
  ss[sl][f] = s; sq[sl][f] = q;
  __syncthreads();
  if (tid < 128){
    msum[(size_t)blockIdx.x * 128 + tid] = ss[0][tid] + ss[1][tid];
    mssq[(size_t)blockIdx.x * 128 + tid] = sq[0][tid] + sq[1][tid];
  }
}

// ---------- BN finalize preamble (redundant per block, replaces k_bnfin) ----------
__device__ __forceinline__ void bn_finalize_lds(const float* __restrict__ msum,
                                                const float* __restrict__ mssq,
                                                const float* __restrict__ gamma,
                                                const float* __restrict__ beta,
                                                float* ssc, float* ssh){
  const int tid = threadIdx.x;
  if (tid < 128){
    float S = 0.f, Q = 0.f;
#pragma unroll
    for (int b = 0; b < MID_BLOCKS; b++){
      S += msum[(size_t)b * 128 + tid];
      Q += mssq[(size_t)b * 128 + tid];
    }
    const float inv = 1.0f / (float)ROWS;
    float mu = S * inv;
    float var = fmaxf(Q * inv - mu * mu, 0.f);
    float rstd = 1.0f / sqrtf(var + 1e-5f);
    float sc = gamma[tid] * rstd;
    ssc[tid] = sc;
    ssh[tid] = fmaf(-mu, sc, beta[tid]);
  }
  __syncthreads();
}

// ---------- prep2: BN1-finalize + pack s1(.)W2 + C2 = t1 @ W2 (9 blocks) ----------
__global__ void k_prep2(const float* __restrict__ msum, const float* __restrict__ mssq,
                        const float* __restrict__ gamma, const float* __restrict__ beta,
                        const float* __restrict__ W2,
                        uint16_t* __restrict__ WP2, float* __restrict__ C2){
  __shared__ float ssc[128];
  __shared__ float ssh[128];
  bn_finalize_lds(msum, mssq, gamma, beta, ssc, ssh);
  if (blockIdx.x < 8){
    pack_w(blockIdx.x * 256 + threadIdx.x, W2, ssc, WP2);
  } else if (threadIdx.x < 128){
    const int j = threadIdx.x;
    float a = 0.f;
    for (int k = 0; k < HID; k++) a = fmaf(ssh[k], W2[(size_t)k * HID + j], a);
    C2[j] = a;
  }
}

// ---------- prepc: BN2-finalize + pack s2(.)Wc + CVC = t2 @ Wc + bc (2 blocks) ----------
__global__ void k_prepc(const float* __restrict__ msum, const float* __restrict__ mssq,
                        const float* __restrict__ gamma, const float* __restrict__ beta,
                        const float* __restrict__ Wc, const float* __restrict__ bc,
                        uint16_t* __restrict__ WPC, float* __restrict__ CVC){
  __shared__ float ssc[128];
  __shared__ float ssh[128];
  bn_finalize_lds(msum, mssq, gamma, beta, ssc, ssh);
  if (blockIdx.x == 0){
    // classifier pack: single c-tile, original col mapping
    int t = threadIdx.x;
    int L = t & 63;
    int s = t >> 6;
    int n = L & 15;
    int k0 = s * 32 + (L >> 4) * 8;
    ushort8 r;
#pragma unroll
    for (int j = 0; j < 8; j++)
      r[j] = f2bf(ssc[k0 + j] * Wc[(size_t)(k0 + j) * OUTD + n]);
    *((ushort8*)(WPC + (size_t)t * 8)) = r;
  } else if (threadIdx.x < OUTD){
    const int j = threadIdx.x;
    float a = bc[j];
    for (int k = 0; k < HID; k++) a = fmaf(ssh[k], Wc[(size_t)k * OUTD + j], a);
    CVC[j] = a;
  }
}

// ---------- launch ----------
extern "C" void kernel_launch(void* const* d_in, const int* in_sizes, int n_in,
                              void* d_out, int out_size, void* d_ws, size_t ws_size,
                              hipStream_t stream){
  const float* x   = (const float*)d_in[0];
  const int*   ei  = (const int*)d_in[1];
  const float* ewp = (const float*)d_in[2];
  const float* W1  = (const float*)d_in[3];
  const float* b1  = (const float*)d_in[4];
  const float* W2  = (const float*)d_in[5];
  const float* b2  = (const float*)d_in[6];
  const float* g1  = (const float*)d_in[7];
  const float* be1 = (const float*)d_in[8];
  const float* g2  = (const float*)d_in[9];
  const float* be2 = (const float*)d_in[10];
  const float* Wc  = (const float*)d_in[11];
  const float* bc  = (const float*)d_in[12];
  float* out = (float*)d_out;

  char* wsb = (char*)d_ws;
  size_t off = 0;
  auto give = [&](size_t bytes) -> void* {
    void* p = wsb + off;
    off = (off + bytes + 255) & ~(size_t)255;
    return p;
  };
  uint16_t* XW  = (uint16_t*)give((size_t)ROWS * 128 * 2);   // planar [b][node][feat]
  uint16_t* Hb  = (uint16_t*)give((size_t)ROWS * 128 * 2);   // planar
  unsigned long long* DC  = (unsigned long long*)give((size_t)N_NODES * 8);
  unsigned long long* EDG = (unsigned long long*)give((size_t)N_EDGES * 8);
  unsigned int* SLOT = (unsigned int*)give((size_t)N_EDGES * 4);
  float* DINV   = (float*)give((size_t)N_NODES * 4);
  int*   RP     = (int*)give((size_t)(N_NODES + 1) * 4);
  int*   BSUM   = (int*)give(1024);
  float* PSUM   = (float*)give((size_t)AGG_BLOCKS * 128 * 4);
  float* PSSQ   = (float*)give((size_t)AGG_BLOCKS * 128 * 4);
  float* MSUM   = (float*)give((size_t)MID_BLOCKS * 128 * 4);
  float* MSSQ   = (float*)give((size_t)MID_BLOCKS * 128 * 4);
  uint16_t* WP1 = (uint16_t*)give((size_t)HID * HID * 2);
  uint16_t* WP2 = (uint16_t*)give((size_t)HID * HID * 2);
  uint16_t* WPC = (uint16_t*)give((size_t)HID * OUTD * 2);
  float* C2     = (float*)give(512);
  float* CVC    = (float*)give(64);
  (void)ws_size; (void)n_in; (void)in_sizes; (void)out_size;

  // 1: zero DC + pack W1
  k_initpack<<<SCAN_BLOCKS + 8, 256, 0, stream>>>(DC, W1, WP1);
  // 2: fused edge atomics (+SLOT) and GEMM1 (overlap, 5:2, NO reg cap)
  k_edge_gemm1<<<EG_BLOCKS, 256, 0, stream>>>(ei, ewp, DC, SLOT, x, WP1, XW);
  // 3-5: CSR build
  k_scan_bsum<<<SCAN_BLOCKS, 256, 0, stream>>>(DC, BSUM, DINV);
  k_scan_write<<<SCAN_BLOCKS, 256, 0, stream>>>(DC, BSUM, RP);
  k_fill<<<(N_EDGES + 255) / 256, 256, 0, stream>>>(ei, ewp, DINV, SLOT, RP, EDG);
  // layer 1 aggregation + BN stats
  k_agg<<<AGG_BLOCKS, 256, 0, stream>>>(XW, RP, EDG, DINV, b1, nullptr, Hb, PSUM, PSSQ);
  k_bnmid<<<MID_BLOCKS, 256, 0, stream>>>(PSUM, PSSQ, MSUM, MSSQ);
  // BN1-finalize + W2 pack + C2
  k_prep2<<<9, 256, 0, stream>>>(MSUM, MSSQ, g1, be1, W2, WP2, C2);
  // layer 2
  k_gemm2<<<GEMM_BLOCKS, 256, 0, stream>>>(Hb, WP2, XW);
  k_agg<<<AGG_BLOCKS, 256, 0, stream>>>(XW, RP, EDG, DINV, b2, C2, Hb, PSUM, PSSQ);
  k_bnmid<<<MID_BLOCKS, 256, 0, stream>>>(PSUM, PSSQ, MSUM, MSSQ);
  // BN2-finalize + Wc pack + CVC
  k_prepc<<<2, 256, 0, stream>>>(MSUM, MSSQ, g2, be2, Wc, bc, WPC, CVC);
  // classifier
  k_cls_mfma<<<GEMM_BLOCKS, 256, 0, stream>>>(Hb, WPC, CVC, out);
}